// Round 1
// baseline (1379.930 us; speedup 1.0000x reference)
//
#include <hip/hip_runtime.h>

#define NN 30000
#define ER 480000
#define ET 510000           // ER + NN self-loops
#define D 128
#define NH 8
#define HD 16
#define NL 7
#define SLOPE 0.2f

// ---------------- CSR build (dst is layer-invariant) ----------------

__global__ void k_zero(int* __restrict__ p, int n) {
    int i = blockIdx.x * 256 + threadIdx.x;
    if (i < n) p[i] = 0;
}

__global__ void k_hist(const int* __restrict__ ei, int* __restrict__ counts) {
    int i = blockIdx.x * 256 + threadIdx.x;
    if (i >= ET) return;
    int dst = (i < ER) ? ei[ER + i] : (i - ER);
    atomicAdd(&counts[dst], 1);
}

__global__ __launch_bounds__(256) void k_scan(const int* __restrict__ counts,
                                              int* __restrict__ offsets,
                                              int* __restrict__ cursor) {
    __shared__ int part[256];
    int t = threadIdx.x;
    const int CH = (NN + 255) / 256;  // 118
    int lo = t * CH;
    int hi = min(lo + CH, NN);
    int s = 0;
    for (int i = lo; i < hi; ++i) s += counts[i];
    part[t] = s;
    __syncthreads();
    if (t == 0) {
        int run = 0;
        for (int i = 0; i < 256; ++i) { int c = part[i]; part[i] = run; run += c; }
    }
    __syncthreads();
    int base = part[t];
    for (int i = lo; i < hi; ++i) {
        offsets[i] = base;
        cursor[i] = base;
        base += counts[i];
    }
    if (t == 255) offsets[NN] = base;   // thread 255's chunk is empty -> base == total
}

__global__ void k_scatter(const int* __restrict__ ei, int* __restrict__ cursor,
                          int* __restrict__ perm) {
    int i = blockIdx.x * 256 + threadIdx.x;
    if (i >= ET) return;
    int dst = (i < ER) ? ei[ER + i] : (i - ER);
    int pos = atomicAdd(&cursor[dst], 1);
    perm[pos] = i;
}

// ---------------- fp32 GEMM: Y[N][128] = X[N][128] @ W[128][128] + b ----------------
// 64x64 tile per 256-thread block, K=128 fully staged in LDS, 4x4 register block.

__global__ __launch_bounds__(256) void k_gemm(const float* __restrict__ X,
                                              const float* __restrict__ W,
                                              const float* __restrict__ b,
                                              float* __restrict__ Y) {
    __shared__ float As[D][68];   // As[k][r] = X[row0+r][k] (transposed; +4 pad)
    __shared__ float Bs[D][68];   // Bs[k][c] = W[k][col0+c]
    const int row0 = blockIdx.x * 64;
    const int col0 = blockIdx.y * 64;
    const int tid = threadIdx.x;
    {
        int r = tid >> 2;             // 0..63
        int kc = (tid & 3) * 4;       // 0,4,8,12
        int row = row0 + r; if (row >= NN) row = NN - 1;
        const float* xp = X + (size_t)row * D;
#pragma unroll
        for (int pass = 0; pass < 8; ++pass) {
            int k = pass * 16 + kc;
            float4 v = *reinterpret_cast<const float4*>(xp + k);
            As[k + 0][r] = v.x; As[k + 1][r] = v.y;
            As[k + 2][r] = v.z; As[k + 3][r] = v.w;
        }
        int c4 = (tid & 15) * 4;      // 0..60
        int kb = tid >> 4;            // 0..15
#pragma unroll
        for (int pass = 0; pass < 8; ++pass) {
            int kk = pass * 16 + kb;
            float4 v = *reinterpret_cast<const float4*>(&W[kk * D + col0 + c4]);
            *reinterpret_cast<float4*>(&Bs[kk][c4]) = v;
        }
    }
    __syncthreads();
    const int tx = (tid & 15) * 4;
    const int ty = (tid >> 4) * 4;
    float acc[4][4] = {};
#pragma unroll 4
    for (int k = 0; k < D; ++k) {
        float4 a = *reinterpret_cast<const float4*>(&As[k][ty]);
        float4 w = *reinterpret_cast<const float4*>(&Bs[k][tx]);
        acc[0][0] += a.x * w.x; acc[0][1] += a.x * w.y; acc[0][2] += a.x * w.z; acc[0][3] += a.x * w.w;
        acc[1][0] += a.y * w.x; acc[1][1] += a.y * w.y; acc[1][2] += a.y * w.z; acc[1][3] += a.y * w.w;
        acc[2][0] += a.z * w.x; acc[2][1] += a.z * w.y; acc[2][2] += a.z * w.z; acc[2][3] += a.z * w.w;
        acc[3][0] += a.w * w.x; acc[3][1] += a.w * w.y; acc[3][2] += a.w * w.z; acc[3][3] += a.w * w.w;
    }
    float4 bb = *reinterpret_cast<const float4*>(&b[col0 + tx]);
#pragma unroll
    for (int i = 0; i < 4; ++i) {
        int row = row0 + ty + i;
        if (row < NN) {
            float4 o;
            o.x = acc[i][0] + bb.x; o.y = acc[i][1] + bb.y;
            o.z = acc[i][2] + bb.z; o.w = acc[i][3] + bb.w;
            *reinterpret_cast<float4*>(&Y[(size_t)row * D + col0 + tx]) = o;
        }
    }
}

// ---------------- per-(edge,head) attention logits ----------------

__global__ void k_edge(const int* __restrict__ ei,
                       const float* __restrict__ xl, const float* __restrict__ xr,
                       const float* __restrict__ att, float* __restrict__ e) {
    int gt = blockIdx.x * 256 + threadIdx.x;
    if (gt >= ET * NH) return;
    int edge = gt >> 3;
    int h = gt & 7;
    int src, dst;
    if (edge < ER) { src = ei[edge]; dst = ei[ER + edge]; }
    else           { src = edge - ER; dst = src; }
    const float4* pl = reinterpret_cast<const float4*>(xl + (size_t)src * D + h * HD);
    const float4* pr = reinterpret_cast<const float4*>(xr + (size_t)dst * D + h * HD);
    const float4* pa = reinterpret_cast<const float4*>(att + h * HD);
    float acc = 0.f;
#pragma unroll
    for (int q = 0; q < 4; ++q) {
        float4 a = pl[q], r = pr[q], w = pa[q];
        float m;
        m = a.x + r.x; m = (m > 0.f) ? m : SLOPE * m; acc += m * w.x;
        m = a.y + r.y; m = (m > 0.f) ? m : SLOPE * m; acc += m * w.y;
        m = a.z + r.z; m = (m > 0.f) ? m : SLOPE * m; acc += m * w.z;
        m = a.w + r.w; m = (m > 0.f) ? m : SLOPE * m; acc += m * w.w;
    }
    e[(size_t)edge * NH + h] = acc;
}

// ---------------- per-node segment softmax + aggregation (CSR, no atomics) ----------------

__global__ __launch_bounds__(64) void k_node(const int* __restrict__ ei,
                       const int* __restrict__ offsets, const int* __restrict__ perm,
                       const float* __restrict__ e, const float* __restrict__ xl,
                       const float* __restrict__ bias, float* __restrict__ xout) {
    int n = blockIdx.x;
    int lane = threadIdx.x;
    int off = offsets[n];
    int deg = offsets[n + 1] - off;
    int h = lane & 7;
    float m = -1e30f;
    for (int i = (lane >> 3); i < deg; i += 8) {
        int eid = perm[off + i];
        m = fmaxf(m, e[(size_t)eid * NH + h]);
    }
    m = fmaxf(m, __shfl_xor(m, 8));
    m = fmaxf(m, __shfl_xor(m, 16));
    m = fmaxf(m, __shfl_xor(m, 32));
    float s = 0.f;
    for (int i = (lane >> 3); i < deg; i += 8) {
        int eid = perm[off + i];
        s += __expf(e[(size_t)eid * NH + h] - m);
    }
    s += __shfl_xor(s, 8); s += __shfl_xor(s, 16); s += __shfl_xor(s, 32);
    __shared__ float em[8], rd[8];
    if (lane < 8) { em[lane] = m; rd[lane] = 1.f / (s + 1e-16f); }
    __syncthreads();
    int h0 = lane >> 4, h1 = 4 + h0;
    float em0 = em[h0], r0 = rd[h0];
    float em1 = em[h1], r1 = rd[h1];
    float a0 = 0.f, a1 = 0.f;
    for (int i = 0; i < deg; ++i) {
        int eid = perm[off + i];
        int src = (eid < ER) ? ei[eid] : (eid - ER);
        float al0 = __expf(e[(size_t)eid * NH + h0] - em0) * r0;
        float al1 = __expf(e[(size_t)eid * NH + h1] - em1) * r1;
        a0 += al0 * xl[(size_t)src * D + lane];
        a1 += al1 * xl[(size_t)src * D + 64 + lane];
    }
    xout[(size_t)n * D + lane] = a0 + bias[lane];
    xout[(size_t)n * D + 64 + lane] = a1 + bias[64 + lane];
}

// ---------------- output head: y[i] = x[i,:] @ Wout + bout, i = 0,1 ----------------

__global__ void k_out(const float* __restrict__ x, const float* __restrict__ Wout,
                      const float* __restrict__ bout, float* __restrict__ y) {
    int lane = threadIdx.x;
#pragma unroll
    for (int i = 0; i < 2; ++i) {
        float v = x[i * D + lane] * Wout[lane] + x[i * D + 64 + lane] * Wout[64 + lane];
        v += __shfl_xor(v, 1); v += __shfl_xor(v, 2); v += __shfl_xor(v, 4);
        v += __shfl_xor(v, 8); v += __shfl_xor(v, 16); v += __shfl_xor(v, 32);
        if (lane == 0) y[i] = v + bout[0];
    }
}

// ---------------- launch ----------------

extern "C" void kernel_launch(void* const* d_in, const int* in_sizes, int n_in,
                              void* d_out, int out_size, void* d_ws, size_t ws_size,
                              hipStream_t stream) {
    const float* x_in = (const float*)d_in[0];
    const int*   ei   = (const int*)d_in[1];
    const float* Wl   = (const float*)d_in[2];
    const float* bl   = (const float*)d_in[3];
    const float* Wr   = (const float*)d_in[4];
    const float* br   = (const float*)d_in[5];
    const float* att  = (const float*)d_in[6];
    const float* bias = (const float*)d_in[7];
    const float* Wout = (const float*)d_in[8];
    const float* bout = (const float*)d_in[9];
    float* y = (float*)d_out;

    char* ws = (char*)d_ws;
    size_t o = 0;
    auto alloc = [&](size_t bytes) -> void* {
        void* p = ws + o;
        o = (o + bytes + 255) & ~(size_t)255;
        return p;
    };
    float* xb0 = (float*)alloc((size_t)NN * D * 4);
    float* xb1 = (float*)alloc((size_t)NN * D * 4);
    float* xl  = (float*)alloc((size_t)NN * D * 4);
    float* xr  = (float*)alloc((size_t)NN * D * 4);
    float* e   = (float*)alloc((size_t)ET * NH * 4);
    int* counts  = (int*)alloc((size_t)NN * 4);
    int* offsets = (int*)alloc(((size_t)NN + 1) * 4);
    int* cursor  = (int*)alloc((size_t)NN * 4);
    int* perm    = (int*)alloc((size_t)ET * 4);
    (void)ws_size; (void)in_sizes; (void)n_in; (void)out_size;

    // CSR by dst (layer-invariant)
    k_zero<<<(NN + 255) / 256, 256, 0, stream>>>(counts, NN);
    k_hist<<<(ET + 255) / 256, 256, 0, stream>>>(ei, counts);
    k_scan<<<1, 256, 0, stream>>>(counts, offsets, cursor);
    k_scatter<<<(ET + 255) / 256, 256, 0, stream>>>(ei, cursor, perm);

    dim3 ggrid((NN + 63) / 64, 2);
    for (int i = 0; i < NL; ++i) {
        const float* xin = (i == 0) ? x_in : ((i & 1) ? xb0 : xb1);
        float* xout = (i & 1) ? xb1 : xb0;
        k_gemm<<<ggrid, 256, 0, stream>>>(xin, Wl + (size_t)i * D * D, bl + i * D, xl);
        k_gemm<<<ggrid, 256, 0, stream>>>(xin, Wr + (size_t)i * D * D, br + i * D, xr);
        k_edge<<<(ET * NH + 255) / 256, 256, 0, stream>>>(ei, xl, xr, att + i * NH * HD, e);
        k_node<<<NN, 64, 0, stream>>>(ei, offsets, perm, e, xl, bias + i * D, xout);
    }
    k_out<<<1, 64, 0, stream>>>(xb0, Wout, bout, y);  // NL=7 odd -> final in xb0
}

// Round 2
// 750.748 us; speedup vs baseline: 1.8381x; 1.8381x over previous
//
#include <hip/hip_runtime.h>

#define NN 30000
#define ER 480000
#define ET 510000           // ER + NN self-loops
#define D 128
#define NH 8
#define HD 16
#define NL 7
#define SLOPE 0.2f

// ---------------- CSR build (dst is layer-invariant) ----------------

__global__ void k_zero(int* __restrict__ p, int n) {
    int i = blockIdx.x * 256 + threadIdx.x;
    if (i < n) p[i] = 0;
}

__global__ void k_hist(const int* __restrict__ ei, int* __restrict__ counts) {
    int i = blockIdx.x * 256 + threadIdx.x;
    if (i >= ET) return;
    int dst = (i < ER) ? ei[ER + i] : (i - ER);
    atomicAdd(&counts[dst], 1);
}

__global__ __launch_bounds__(256) void k_scan(const int* __restrict__ counts,
                                              int* __restrict__ offsets,
                                              int* __restrict__ cursor) {
    __shared__ int part[256];
    int t = threadIdx.x;
    const int CH = (NN + 255) / 256;  // 118
    int lo = t * CH;
    int hi = min(lo + CH, NN);
    int s = 0;
    for (int i = lo; i < hi; ++i) s += counts[i];
    part[t] = s;
    __syncthreads();
    if (t == 0) {
        int run = 0;
        for (int i = 0; i < 256; ++i) { int c = part[i]; part[i] = run; run += c; }
    }
    __syncthreads();
    int base = part[t];
    for (int i = lo; i < hi; ++i) {
        offsets[i] = base;
        cursor[i] = base;
        base += counts[i];
    }
    if (t == 255) offsets[NN] = base;
}

// scatter: also resolve src node id so the hot loop has a single flat array
__global__ void k_scatter(const int* __restrict__ ei, int* __restrict__ cursor,
                          int* __restrict__ srcs) {
    int i = blockIdx.x * 256 + threadIdx.x;
    if (i >= ET) return;
    int src, dst;
    if (i < ER) { src = ei[i]; dst = ei[ER + i]; }
    else        { src = i - ER; dst = src; }
    int pos = atomicAdd(&cursor[dst], 1);
    srcs[pos] = src;
}

// ---------------- fp32 GEMM: xl = X@Wl+bl and xr = X@Wr+br in one dispatch ----------------
// 64x64 tile per 256-thread block, K=128 fully staged in LDS, 4x4 register block.
// blockIdx.z selects (Wl->xl) vs (Wr->xr).

__global__ __launch_bounds__(256) void k_gemm2(const float* __restrict__ X,
                                               const float* __restrict__ Wl,
                                               const float* __restrict__ bl,
                                               const float* __restrict__ Wr,
                                               const float* __restrict__ br,
                                               float* __restrict__ xl,
                                               float* __restrict__ xr) {
    const float* W = blockIdx.z ? Wr : Wl;
    const float* b = blockIdx.z ? br : bl;
    float* Y = blockIdx.z ? xr : xl;
    __shared__ float As[D][68];   // As[k][r] = X[row0+r][k] (transposed; +4 pad)
    __shared__ float Bs[D][68];   // Bs[k][c] = W[k][col0+c]
    const int row0 = blockIdx.x * 64;
    const int col0 = blockIdx.y * 64;
    const int tid = threadIdx.x;
    {
        int r = tid >> 2;             // 0..63
        int kc = (tid & 3) * 4;       // 0,4,8,12
        int row = row0 + r; if (row >= NN) row = NN - 1;
        const float* xp = X + (size_t)row * D;
#pragma unroll
        for (int pass = 0; pass < 8; ++pass) {
            int k = pass * 16 + kc;
            float4 v = *reinterpret_cast<const float4*>(xp + k);
            As[k + 0][r] = v.x; As[k + 1][r] = v.y;
            As[k + 2][r] = v.z; As[k + 3][r] = v.w;
        }
        int c4 = (tid & 15) * 4;      // 0..60
        int kb = tid >> 4;            // 0..15
#pragma unroll
        for (int pass = 0; pass < 8; ++pass) {
            int kk = pass * 16 + kb;
            float4 v = *reinterpret_cast<const float4*>(&W[kk * D + col0 + c4]);
            *reinterpret_cast<float4*>(&Bs[kk][c4]) = v;
        }
    }
    __syncthreads();
    const int tx = (tid & 15) * 4;
    const int ty = (tid >> 4) * 4;
    float acc[4][4] = {};
#pragma unroll 4
    for (int k = 0; k < D; ++k) {
        float4 a = *reinterpret_cast<const float4*>(&As[k][ty]);
        float4 w = *reinterpret_cast<const float4*>(&Bs[k][tx]);
        acc[0][0] += a.x * w.x; acc[0][1] += a.x * w.y; acc[0][2] += a.x * w.z; acc[0][3] += a.x * w.w;
        acc[1][0] += a.y * w.x; acc[1][1] += a.y * w.y; acc[1][2] += a.y * w.z; acc[1][3] += a.y * w.w;
        acc[2][0] += a.z * w.x; acc[2][1] += a.z * w.y; acc[2][2] += a.z * w.z; acc[2][3] += a.z * w.w;
        acc[3][0] += a.w * w.x; acc[3][1] += a.w * w.y; acc[3][2] += a.w * w.z; acc[3][3] += a.w * w.w;
    }
    float4 bb = *reinterpret_cast<const float4*>(&b[col0 + tx]);
#pragma unroll
    for (int i = 0; i < 4; ++i) {
        int row = row0 + ty + i;
        if (row < NN) {
            float4 o;
            o.x = acc[i][0] + bb.x; o.y = acc[i][1] + bb.y;
            o.z = acc[i][2] + bb.z; o.w = acc[i][3] + bb.w;
            *reinterpret_cast<float4*>(&Y[(size_t)row * D + col0 + tx]) = o;
        }
    }
}

// ---------------- fused edge-score + online-softmax + aggregation ----------------
// One wave per destination node; 4 nodes per 256-thread block.
// lane l holds feature dims {l, 64+l}; head of dim d is d>>4.
// Online softmax: running max m, denom s, accumulator acc, rescaled on max change.

#define FUSED_UPDATE(v0, v1)                                                    \
    {                                                                           \
        float t0 = v0 + r0;                                                     \
        t0 = (fmaxf(t0, 0.f) + SLOPE * fminf(t0, 0.f)) * a0;                    \
        float t1 = v1 + r1;                                                     \
        t1 = (fmaxf(t1, 0.f) + SLOPE * fminf(t1, 0.f)) * a1;                    \
        t0 += __shfl_xor(t0, 1);  t1 += __shfl_xor(t1, 1);                      \
        t0 += __shfl_xor(t0, 2);  t1 += __shfl_xor(t1, 2);                      \
        t0 += __shfl_xor(t0, 4);  t1 += __shfl_xor(t1, 4);                      \
        t0 += __shfl_xor(t0, 8);  t1 += __shfl_xor(t1, 8);                      \
        float d0 = t0 - m0;                                                     \
        float ex0 = __expf(-fabsf(d0));                                         \
        float p0 = (d0 <= 0.f) ? ex0 : 1.f;                                     \
        float c0 = (d0 <= 0.f) ? 1.f : ex0;                                     \
        m0 = fmaxf(m0, t0);                                                     \
        s0 = s0 * c0 + p0;                                                      \
        acc0 = acc0 * c0 + p0 * (v0);                                           \
        float d1 = t1 - m1;                                                     \
        float ex1 = __expf(-fabsf(d1));                                         \
        float p1 = (d1 <= 0.f) ? ex1 : 1.f;                                     \
        float c1 = (d1 <= 0.f) ? 1.f : ex1;                                     \
        m1 = fmaxf(m1, t1);                                                     \
        s1 = s1 * c1 + p1;                                                      \
        acc1 = acc1 * c1 + p1 * (v1);                                           \
    }

__global__ __launch_bounds__(256) void k_fused(const int* __restrict__ offsets,
                                               const int* __restrict__ srcs,
                                               const float* __restrict__ xl,
                                               const float* __restrict__ xr,
                                               const float* __restrict__ att,
                                               const float* __restrict__ bias,
                                               float* __restrict__ xout) {
    const int lane = threadIdx.x & 63;
    const int n = blockIdx.x * 4 + (threadIdx.x >> 6);
    const int off = offsets[n];
    const int deg = offsets[n + 1] - off;

    const float r0 = xr[(size_t)n * D + lane];
    const float r1 = xr[(size_t)n * D + 64 + lane];
    const float a0 = att[lane];
    const float a1 = att[64 + lane];

    float m0 = -1e30f, m1 = -1e30f;
    float s0 = 0.f, s1 = 0.f;
    float acc0 = 0.f, acc1 = 0.f;

    int i = 0;
    // peel to 16B alignment of &srcs[off+i]
    int peel = (4 - (off & 3)) & 3;
    if (peel > deg) peel = deg;
    for (; i < peel; ++i) {
        int src = srcs[off + i];
        const float* p = xl + (size_t)src * D;
        float v0 = p[lane];
        float v1 = p[64 + lane];
        FUSED_UPDATE(v0, v1);
    }
    for (; i + 4 <= deg; i += 4) {
        int4 sq = *reinterpret_cast<const int4*>(&srcs[off + i]);
        int sa[4] = {sq.x, sq.y, sq.z, sq.w};
        float v0[4], v1[4];
#pragma unroll
        for (int j = 0; j < 4; ++j) {
            const float* p = xl + (size_t)sa[j] * D;
            v0[j] = p[lane];
            v1[j] = p[64 + lane];
        }
#pragma unroll
        for (int j = 0; j < 4; ++j) {
            FUSED_UPDATE(v0[j], v1[j]);
        }
    }
    for (; i < deg; ++i) {
        int src = srcs[off + i];
        const float* p = xl + (size_t)src * D;
        float v0 = p[lane];
        float v1 = p[64 + lane];
        FUSED_UPDATE(v0, v1);
    }

    float o0 = acc0 / (s0 + 1e-16f) + bias[lane];
    float o1 = acc1 / (s1 + 1e-16f) + bias[64 + lane];
    xout[(size_t)n * D + lane] = o0;
    xout[(size_t)n * D + 64 + lane] = o1;
}

// ---------------- output head: y[i] = x[i,:] @ Wout + bout, i = 0,1 ----------------

__global__ void k_out(const float* __restrict__ x, const float* __restrict__ Wout,
                      const float* __restrict__ bout, float* __restrict__ y) {
    int lane = threadIdx.x;
#pragma unroll
    for (int i = 0; i < 2; ++i) {
        float v = x[i * D + lane] * Wout[lane] + x[i * D + 64 + lane] * Wout[64 + lane];
        v += __shfl_xor(v, 1); v += __shfl_xor(v, 2); v += __shfl_xor(v, 4);
        v += __shfl_xor(v, 8); v += __shfl_xor(v, 16); v += __shfl_xor(v, 32);
        if (lane == 0) y[i] = v + bout[0];
    }
}

// ---------------- launch ----------------

extern "C" void kernel_launch(void* const* d_in, const int* in_sizes, int n_in,
                              void* d_out, int out_size, void* d_ws, size_t ws_size,
                              hipStream_t stream) {
    const float* x_in = (const float*)d_in[0];
    const int*   ei   = (const int*)d_in[1];
    const float* Wl   = (const float*)d_in[2];
    const float* bl   = (const float*)d_in[3];
    const float* Wr   = (const float*)d_in[4];
    const float* br   = (const float*)d_in[5];
    const float* att  = (const float*)d_in[6];
    const float* bias = (const float*)d_in[7];
    const float* Wout = (const float*)d_in[8];
    const float* bout = (const float*)d_in[9];
    float* y = (float*)d_out;

    char* ws = (char*)d_ws;
    size_t o = 0;
    auto alloc = [&](size_t bytes) -> void* {
        void* p = ws + o;
        o = (o + bytes + 255) & ~(size_t)255;
        return p;
    };
    float* xb0 = (float*)alloc((size_t)NN * D * 4);
    float* xb1 = (float*)alloc((size_t)NN * D * 4);
    float* xl  = (float*)alloc((size_t)NN * D * 4);
    float* xr  = (float*)alloc((size_t)NN * D * 4);
    int* counts  = (int*)alloc((size_t)NN * 4);
    int* offsets = (int*)alloc(((size_t)NN + 1) * 4);
    int* cursor  = (int*)alloc((size_t)NN * 4);
    int* srcs    = (int*)alloc((size_t)ET * 4);
    (void)ws_size; (void)in_sizes; (void)n_in; (void)out_size;

    // CSR by dst with resolved srcs (layer-invariant)
    k_zero<<<(NN + 255) / 256, 256, 0, stream>>>(counts, NN);
    k_hist<<<(ET + 255) / 256, 256, 0, stream>>>(ei, counts);
    k_scan<<<1, 256, 0, stream>>>(counts, offsets, cursor);
    k_scatter<<<(ET + 255) / 256, 256, 0, stream>>>(ei, cursor, srcs);

    dim3 ggrid((NN + 63) / 64, 2, 2);
    for (int i = 0; i < NL; ++i) {
        const float* xin = (i == 0) ? x_in : ((i & 1) ? xb0 : xb1);
        float* xout = (i & 1) ? xb1 : xb0;
        k_gemm2<<<ggrid, 256, 0, stream>>>(xin, Wl + (size_t)i * D * D, bl + i * D,
                                           Wr + (size_t)i * D * D, br + i * D, xl, xr);
        k_fused<<<NN / 4, 256, 0, stream>>>(offsets, srcs, xl, xr,
                                            att + i * NH * HD, bias + i * D, xout);
    }
    k_out<<<1, 64, 0, stream>>>(xb0, Wout, bout, y);  // NL=7 odd -> final in xb0
}

// Round 3
// 696.107 us; speedup vs baseline: 1.9824x; 1.0785x over previous
//
#include <hip/hip_runtime.h>

#define NN 30000
#define ER 480000
#define ET 510000           // ER + NN self-loops
#define D 128
#define NH 8
#define HD 16
#define NL 7
#define SLOPE 0.2f
#define NB_SCAN 118         // ceil(NN/256)

// ---------------- CSR build (dst is layer-invariant) ----------------

__global__ void k_zero(int* __restrict__ p, int n) {
    int i = blockIdx.x * 256 + threadIdx.x;
    if (i < n) p[i] = 0;
}

__global__ void k_hist(const int* __restrict__ ei, int* __restrict__ counts) {
    int i = blockIdx.x * 256 + threadIdx.x;
    if (i >= ET) return;
    int dst = (i < ER) ? ei[ER + i] : (i - ER);
    atomicAdd(&counts[dst], 1);
}

// stage 1: per-block local exclusive scan + block totals
__global__ __launch_bounds__(256) void k_scan1(const int* __restrict__ counts,
                                               int* __restrict__ offsets,
                                               int* __restrict__ partials) {
    int t = threadIdx.x;
    int i = blockIdx.x * 256 + t;
    int v = (i < NN) ? counts[i] : 0;
    int lane = t & 63;
    int incl = v;
#pragma unroll
    for (int d = 1; d < 64; d <<= 1) {
        int u = __shfl_up(incl, d);
        if (lane >= d) incl += u;
    }
    __shared__ int ws[4];
    if (lane == 63) ws[t >> 6] = incl;
    __syncthreads();
    int wid = t >> 6;
    int base = 0;
    if (wid > 0) base += ws[0];
    if (wid > 1) base += ws[1];
    if (wid > 2) base += ws[2];
    if (i < NN) offsets[i] = base + incl - v;      // local exclusive
    if (t == 255) partials[blockIdx.x] = base + incl;  // block total
}

// stage 2: scan the 118 block totals (in place -> exclusive bases), write grand total
__global__ __launch_bounds__(128) void k_scan2(int* __restrict__ partials,
                                               int* __restrict__ offsets) {
    int t = threadIdx.x;
    int v = (t < NB_SCAN) ? partials[t] : 0;
    int lane = t & 63;
    int incl = v;
#pragma unroll
    for (int d = 1; d < 64; d <<= 1) {
        int u = __shfl_up(incl, d);
        if (lane >= d) incl += u;
    }
    __shared__ int w0;
    if (t == 63) w0 = incl;
    __syncthreads();
    int base = (t >= 64) ? w0 : 0;
    if (t < NB_SCAN) partials[t] = base + incl - v;  // exclusive base per block
    if (t == 127) offsets[NN] = base + incl;          // grand total (= ET)
}

// stage 3: add block base; init cursor
__global__ void k_scan3(const int* __restrict__ partials, int* __restrict__ offsets,
                        int* __restrict__ cursor) {
    int i = blockIdx.x * 256 + threadIdx.x;
    if (i < NN) {
        int o = offsets[i] + partials[blockIdx.x];
        offsets[i] = o;
        cursor[i] = o;
    }
}

// scatter: resolve src node id so the hot loop has a single flat array
__global__ void k_scatter(const int* __restrict__ ei, int* __restrict__ cursor,
                          int* __restrict__ srcs) {
    int i = blockIdx.x * 256 + threadIdx.x;
    if (i >= ET) return;
    int src, dst;
    if (i < ER) { src = ei[i]; dst = ei[ER + i]; }
    else        { src = i - ER; dst = src; }
    int pos = atomicAdd(&cursor[dst], 1);
    srcs[pos] = src;
}

// ---------------- fp32 GEMM, one pass over X: xl = X@Wl+bl, xr = X@Wr+br ----------------
// 64-row tile per 256-thread block; X tile staged once in LDS; loop 4 col-chunks
// (Wl[:,0:64], Wl[:,64:128], Wr[:,0:64], Wr[:,64:128]) staging each W chunk.

__global__ __launch_bounds__(256) void k_gemm(const float* __restrict__ X,
                                              const float* __restrict__ Wl,
                                              const float* __restrict__ bl,
                                              const float* __restrict__ Wr,
                                              const float* __restrict__ br,
                                              float* __restrict__ xl,
                                              float* __restrict__ xr) {
    __shared__ float Xs[D][68];   // Xs[k][r] = X[row0+r][k] (transposed; +4 pad)
    __shared__ float Ws[D][68];   // Ws[k][c] = W[k][col0+c] for current chunk
    const int row0 = blockIdx.x * 64;
    const int tid = threadIdx.x;
    {
        int r = tid >> 2;             // 0..63
        int kc = (tid & 3) * 4;       // 0,4,8,12
        int row = row0 + r; if (row >= NN) row = NN - 1;
        const float* xp = X + (size_t)row * D;
#pragma unroll
        for (int pass = 0; pass < 8; ++pass) {
            int k = pass * 16 + kc;
            float4 v = *reinterpret_cast<const float4*>(xp + k);
            Xs[k + 0][r] = v.x; Xs[k + 1][r] = v.y;
            Xs[k + 2][r] = v.z; Xs[k + 3][r] = v.w;
        }
    }
    const int tx = (tid & 15) * 4;
    const int ty = (tid >> 4) * 4;
    const int c4 = (tid & 15) * 4;
    const int kb = tid >> 4;
#pragma unroll
    for (int chunk = 0; chunk < 4; ++chunk) {
        const float* W = (chunk < 2) ? Wl : Wr;
        const float* b = (chunk < 2) ? bl : br;
        float* Y = (chunk < 2) ? xl : xr;
        const int col0 = (chunk & 1) * 64;
        __syncthreads();   // previous chunk's readers done (chunk 0: no-op ordering)
#pragma unroll
        for (int pass = 0; pass < 8; ++pass) {
            int kk = pass * 16 + kb;
            float4 v = *reinterpret_cast<const float4*>(&W[kk * D + col0 + c4]);
            *reinterpret_cast<float4*>(&Ws[kk][c4]) = v;
        }
        __syncthreads();   // Ws (and, first iter, Xs) staged
        float acc[4][4] = {};
#pragma unroll 4
        for (int k = 0; k < D; ++k) {
            float4 a = *reinterpret_cast<const float4*>(&Xs[k][ty]);
            float4 w = *reinterpret_cast<const float4*>(&Ws[k][tx]);
            acc[0][0] += a.x * w.x; acc[0][1] += a.x * w.y; acc[0][2] += a.x * w.z; acc[0][3] += a.x * w.w;
            acc[1][0] += a.y * w.x; acc[1][1] += a.y * w.y; acc[1][2] += a.y * w.z; acc[1][3] += a.y * w.w;
            acc[2][0] += a.z * w.x; acc[2][1] += a.z * w.y; acc[2][2] += a.z * w.z; acc[2][3] += a.z * w.w;
            acc[3][0] += a.w * w.x; acc[3][1] += a.w * w.y; acc[3][2] += a.w * w.z; acc[3][3] += a.w * w.w;
        }
        float4 bb = *reinterpret_cast<const float4*>(&b[col0 + tx]);
#pragma unroll
        for (int i = 0; i < 4; ++i) {
            int row = row0 + ty + i;
            if (row < NN) {
                float4 o;
                o.x = acc[i][0] + bb.x; o.y = acc[i][1] + bb.y;
                o.z = acc[i][2] + bb.z; o.w = acc[i][3] + bb.w;
                *reinterpret_cast<float4*>(&Y[(size_t)row * D + col0 + tx]) = o;
            }
        }
    }
}

// ---------------- fused edge-score + online-softmax + aggregation ----------------
// One wave per destination node; 4 nodes per 256-thread block.
// lane l holds feature dims {l, 64+l}; head of dim d is d>>4.

#define FUSED_UPDATE(v0, v1)                                                    \
    {                                                                           \
        float t0 = v0 + r0;                                                     \
        t0 = (fmaxf(t0, 0.f) + SLOPE * fminf(t0, 0.f)) * a0;                    \
        float t1 = v1 + r1;                                                     \
        t1 = (fmaxf(t1, 0.f) + SLOPE * fminf(t1, 0.f)) * a1;                    \
        t0 += __shfl_xor(t0, 1);  t1 += __shfl_xor(t1, 1);                      \
        t0 += __shfl_xor(t0, 2);  t1 += __shfl_xor(t1, 2);                      \
        t0 += __shfl_xor(t0, 4);  t1 += __shfl_xor(t1, 4);                      \
        t0 += __shfl_xor(t0, 8);  t1 += __shfl_xor(t1, 8);                      \
        float d0 = t0 - m0;                                                     \
        float ex0 = __expf(-fabsf(d0));                                         \
        float p0 = (d0 <= 0.f) ? ex0 : 1.f;                                     \
        float c0 = (d0 <= 0.f) ? 1.f : ex0;                                     \
        m0 = fmaxf(m0, t0);                                                     \
        s0 = s0 * c0 + p0;                                                      \
        acc0 = acc0 * c0 + p0 * (v0);                                           \
        float d1 = t1 - m1;                                                     \
        float ex1 = __expf(-fabsf(d1));                                         \
        float p1 = (d1 <= 0.f) ? ex1 : 1.f;                                     \
        float c1 = (d1 <= 0.f) ? 1.f : ex1;                                     \
        m1 = fmaxf(m1, t1);                                                     \
        s1 = s1 * c1 + p1;                                                      \
        acc1 = acc1 * c1 + p1 * (v1);                                           \
    }

__global__ __launch_bounds__(256) void k_fused(const int* __restrict__ offsets,
                                               const int* __restrict__ srcs,
                                               const float* __restrict__ xl,
                                               const float* __restrict__ xr,
                                               const float* __restrict__ att,
                                               const float* __restrict__ bias,
                                               float* __restrict__ xout) {
    const int lane = threadIdx.x & 63;
    const int n = blockIdx.x * 4 + (threadIdx.x >> 6);
    const int off = offsets[n];
    const int deg = offsets[n + 1] - off;

    const float r0 = xr[(size_t)n * D + lane];
    const float r1 = xr[(size_t)n * D + 64 + lane];
    const float a0 = att[lane];
    const float a1 = att[64 + lane];

    float m0 = -1e30f, m1 = -1e30f;
    float s0 = 0.f, s1 = 0.f;
    float acc0 = 0.f, acc1 = 0.f;

    int i = 0;
    int peel = (4 - (off & 3)) & 3;
    if (peel > deg) peel = deg;
    for (; i < peel; ++i) {
        int src = srcs[off + i];
        const float* p = xl + (size_t)src * D;
        float v0 = p[lane];
        float v1 = p[64 + lane];
        FUSED_UPDATE(v0, v1);
    }
    for (; i + 8 <= deg; i += 8) {
        int4 sq0 = *reinterpret_cast<const int4*>(&srcs[off + i]);
        int4 sq1 = *reinterpret_cast<const int4*>(&srcs[off + i + 4]);
        int sa[8] = {sq0.x, sq0.y, sq0.z, sq0.w, sq1.x, sq1.y, sq1.z, sq1.w};
        float v0[8], v1[8];
#pragma unroll
        for (int j = 0; j < 8; ++j) {
            const float* p = xl + (size_t)sa[j] * D;
            v0[j] = p[lane];
            v1[j] = p[64 + lane];
        }
#pragma unroll
        for (int j = 0; j < 8; ++j) {
            FUSED_UPDATE(v0[j], v1[j]);
        }
    }
    for (; i + 4 <= deg; i += 4) {
        int4 sq = *reinterpret_cast<const int4*>(&srcs[off + i]);
        int sa[4] = {sq.x, sq.y, sq.z, sq.w};
        float v0[4], v1[4];
#pragma unroll
        for (int j = 0; j < 4; ++j) {
            const float* p = xl + (size_t)sa[j] * D;
            v0[j] = p[lane];
            v1[j] = p[64 + lane];
        }
#pragma unroll
        for (int j = 0; j < 4; ++j) {
            FUSED_UPDATE(v0[j], v1[j]);
        }
    }
    for (; i < deg; ++i) {
        int src = srcs[off + i];
        const float* p = xl + (size_t)src * D;
        float v0 = p[lane];
        float v1 = p[64 + lane];
        FUSED_UPDATE(v0, v1);
    }

    float o0 = acc0 / (s0 + 1e-16f) + bias[lane];
    float o1 = acc1 / (s1 + 1e-16f) + bias[64 + lane];
    xout[(size_t)n * D + lane] = o0;
    xout[(size_t)n * D + 64 + lane] = o1;
}

// ---------------- output head: y[i] = x[i,:] @ Wout + bout, i = 0,1 ----------------

__global__ void k_out(const float* __restrict__ x, const float* __restrict__ Wout,
                      const float* __restrict__ bout, float* __restrict__ y) {
    int lane = threadIdx.x;
#pragma unroll
    for (int i = 0; i < 2; ++i) {
        float v = x[i * D + lane] * Wout[lane] + x[i * D + 64 + lane] * Wout[64 + lane];
        v += __shfl_xor(v, 1); v += __shfl_xor(v, 2); v += __shfl_xor(v, 4);
        v += __shfl_xor(v, 8); v += __shfl_xor(v, 16); v += __shfl_xor(v, 32);
        if (lane == 0) y[i] = v + bout[0];
    }
}

// ---------------- launch ----------------

extern "C" void kernel_launch(void* const* d_in, const int* in_sizes, int n_in,
                              void* d_out, int out_size, void* d_ws, size_t ws_size,
                              hipStream_t stream) {
    const float* x_in = (const float*)d_in[0];
    const int*   ei   = (const int*)d_in[1];
    const float* Wl   = (const float*)d_in[2];
    const float* bl   = (const float*)d_in[3];
    const float* Wr   = (const float*)d_in[4];
    const float* br   = (const float*)d_in[5];
    const float* att  = (const float*)d_in[6];
    const float* bias = (const float*)d_in[7];
    const float* Wout = (const float*)d_in[8];
    const float* bout = (const float*)d_in[9];
    float* y = (float*)d_out;

    char* ws = (char*)d_ws;
    size_t o = 0;
    auto alloc = [&](size_t bytes) -> void* {
        void* p = ws + o;
        o = (o + bytes + 255) & ~(size_t)255;
        return p;
    };
    float* xb0 = (float*)alloc((size_t)NN * D * 4);
    float* xb1 = (float*)alloc((size_t)NN * D * 4);
    float* xl  = (float*)alloc((size_t)NN * D * 4);
    float* xr  = (float*)alloc((size_t)NN * D * 4);
    int* counts   = (int*)alloc((size_t)NN * 4);
    int* offsets  = (int*)alloc(((size_t)NN + 1) * 4);
    int* cursor   = (int*)alloc((size_t)NN * 4);
    int* srcs     = (int*)alloc((size_t)ET * 4);
    int* partials = (int*)alloc(256 * 4);
    (void)ws_size; (void)in_sizes; (void)n_in; (void)out_size;

    // CSR by dst with resolved srcs (layer-invariant)
    k_zero<<<NB_SCAN, 256, 0, stream>>>(counts, NN);
    k_hist<<<(ET + 255) / 256, 256, 0, stream>>>(ei, counts);
    k_scan1<<<NB_SCAN, 256, 0, stream>>>(counts, offsets, partials);
    k_scan2<<<1, 128, 0, stream>>>(partials, offsets);
    k_scan3<<<NB_SCAN, 256, 0, stream>>>(partials, offsets, cursor);
    k_scatter<<<(ET + 255) / 256, 256, 0, stream>>>(ei, cursor, srcs);

    const int ggrid = (NN + 63) / 64;
    for (int i = 0; i < NL; ++i) {
        const float* xin = (i == 0) ? x_in : ((i & 1) ? xb0 : xb1);
        float* xout = (i & 1) ? xb1 : xb0;
        k_gemm<<<ggrid, 256, 0, stream>>>(xin, Wl + (size_t)i * D * D, bl + i * D,
                                          Wr + (size_t)i * D * D, br + i * D, xl, xr);
        k_fused<<<NN / 4, 256, 0, stream>>>(offsets, srcs, xl, xr,
                                            att + i * NH * HD, bias + i * D, xout);
    }
    k_out<<<1, 64, 0, stream>>>(xb0, Wout, bout, y);  // NL=7 odd -> final in xb0
}

// Round 5
// 559.036 us; speedup vs baseline: 2.4684x; 1.2452x over previous
//
#include <hip/hip_runtime.h>
#include <hip/hip_fp16.h>

#define NN 30000
#define ER 480000
#define ET 510000           // ER + NN self-loops
#define D 128
#define NH 8
#define HD 16
#define NL 7
#define SLOPE 0.2f
#define NB_SCAN 118         // ceil(NN/256)

typedef unsigned int uint32;
typedef unsigned short ushort;

// ---------------- CSR build (dst is layer-invariant) ----------------

__global__ void k_zero(int* __restrict__ p, int n) {
    int i = blockIdx.x * 256 + threadIdx.x;
    if (i < n) p[i] = 0;
}

__global__ void k_hist(const int* __restrict__ ei, int* __restrict__ counts) {
    int i = blockIdx.x * 256 + threadIdx.x;
    if (i >= ET) return;
    int dst = (i < ER) ? ei[ER + i] : (i - ER);
    atomicAdd(&counts[dst], 1);
}

__global__ __launch_bounds__(256) void k_scan1(const int* __restrict__ counts,
                                               int* __restrict__ offsets,
                                               int* __restrict__ partials) {
    int t = threadIdx.x;
    int i = blockIdx.x * 256 + t;
    int v = (i < NN) ? counts[i] : 0;
    int lane = t & 63;
    int incl = v;
#pragma unroll
    for (int d = 1; d < 64; d <<= 1) {
        int u = __shfl_up(incl, d);
        if (lane >= d) incl += u;
    }
    __shared__ int ws[4];
    if (lane == 63) ws[t >> 6] = incl;
    __syncthreads();
    int wid = t >> 6;
    int base = 0;
    if (wid > 0) base += ws[0];
    if (wid > 1) base += ws[1];
    if (wid > 2) base += ws[2];
    if (i < NN) offsets[i] = base + incl - v;
    if (t == 255) partials[blockIdx.x] = base + incl;
}

__global__ __launch_bounds__(128) void k_scan2(int* __restrict__ partials,
                                               int* __restrict__ offsets) {
    int t = threadIdx.x;
    int v = (t < NB_SCAN) ? partials[t] : 0;
    int lane = t & 63;
    int incl = v;
#pragma unroll
    for (int d = 1; d < 64; d <<= 1) {
        int u = __shfl_up(incl, d);
        if (lane >= d) incl += u;
    }
    __shared__ int w0;
    if (t == 63) w0 = incl;
    __syncthreads();
    int base = (t >= 64) ? w0 : 0;
    if (t < NB_SCAN) partials[t] = base + incl - v;
    if (t == 127) offsets[NN] = base + incl;
}

__global__ void k_scan3(const int* __restrict__ partials, int* __restrict__ offsets,
                        int* __restrict__ cursor) {
    int i = blockIdx.x * 256 + threadIdx.x;
    if (i < NN) {
        int o = offsets[i] + partials[blockIdx.x];
        offsets[i] = o;
        cursor[i] = o;
    }
}

__global__ void k_scatter(const int* __restrict__ ei, int* __restrict__ cursor,
                          int* __restrict__ srcs) {
    int i = blockIdx.x * 256 + threadIdx.x;
    if (i >= ET) return;
    int src, dst;
    if (i < ER) { src = ei[i]; dst = ei[ER + i]; }
    else        { src = i - ER; dst = src; }
    int pos = atomicAdd(&cursor[dst], 1);
    srcs[pos] = src;
}

// ---------------- fp32 GEMM, one pass over X ----------------
// xl (fp16-packed rows) = X@Wl+bl ; xr (fp32) = X@Wr+br.

__global__ __launch_bounds__(256) void k_gemm(const float* __restrict__ X,
                                              const float* __restrict__ Wl,
                                              const float* __restrict__ bl,
                                              const float* __restrict__ Wr,
                                              const float* __restrict__ br,
                                              ushort* __restrict__ xlh,
                                              float* __restrict__ xr) {
    __shared__ float Xs[D][68];
    __shared__ float Ws[D][68];
    const int row0 = blockIdx.x * 64;
    const int tid = threadIdx.x;
    {
        int r = tid >> 2;
        int kc = (tid & 3) * 4;
        int row = row0 + r; if (row >= NN) row = NN - 1;
        const float* xp = X + (size_t)row * D;
#pragma unroll
        for (int pass = 0; pass < 8; ++pass) {
            int k = pass * 16 + kc;
            float4 v = *reinterpret_cast<const float4*>(xp + k);
            Xs[k + 0][r] = v.x; Xs[k + 1][r] = v.y;
            Xs[k + 2][r] = v.z; Xs[k + 3][r] = v.w;
        }
    }
    const int tx = (tid & 15) * 4;
    const int ty = (tid >> 4) * 4;
    const int c4 = (tid & 15) * 4;
    const int kb = tid >> 4;
#pragma unroll
    for (int chunk = 0; chunk < 4; ++chunk) {
        const float* W = (chunk < 2) ? Wl : Wr;
        const float* b = (chunk < 2) ? bl : br;
        const int col0 = (chunk & 1) * 64;
        __syncthreads();
#pragma unroll
        for (int pass = 0; pass < 8; ++pass) {
            int kk = pass * 16 + kb;
            float4 v = *reinterpret_cast<const float4*>(&W[kk * D + col0 + c4]);
            *reinterpret_cast<float4*>(&Ws[kk][c4]) = v;
        }
        __syncthreads();
        float acc[4][4] = {};
#pragma unroll 4
        for (int k = 0; k < D; ++k) {
            float4 a = *reinterpret_cast<const float4*>(&Xs[k][ty]);
            float4 w = *reinterpret_cast<const float4*>(&Ws[k][tx]);
            acc[0][0] += a.x * w.x; acc[0][1] += a.x * w.y; acc[0][2] += a.x * w.z; acc[0][3] += a.x * w.w;
            acc[1][0] += a.y * w.x; acc[1][1] += a.y * w.y; acc[1][2] += a.y * w.z; acc[1][3] += a.y * w.w;
            acc[2][0] += a.z * w.x; acc[2][1] += a.z * w.y; acc[2][2] += a.z * w.z; acc[2][3] += a.z * w.w;
            acc[3][0] += a.w * w.x; acc[3][1] += a.w * w.y; acc[3][2] += a.w * w.z; acc[3][3] += a.w * w.w;
        }
        float4 bb = *reinterpret_cast<const float4*>(&b[col0 + tx]);
#pragma unroll
        for (int i = 0; i < 4; ++i) {
            int row = row0 + ty + i;
            if (row >= NN) continue;
            float o0 = acc[i][0] + bb.x, o1 = acc[i][1] + bb.y;
            float o2 = acc[i][2] + bb.z, o3 = acc[i][3] + bb.w;
            if (chunk < 2) {
                ushort4 u;
                u.x = __half_as_ushort(__float2half_rn(o0));
                u.y = __half_as_ushort(__float2half_rn(o1));
                u.z = __half_as_ushort(__float2half_rn(o2));
                u.w = __half_as_ushort(__float2half_rn(o3));
                *reinterpret_cast<ushort4*>(&xlh[(size_t)row * D + col0 + tx]) = u;
            } else {
                float4 o = {o0, o1, o2, o3};
                *reinterpret_cast<float4*>(&xr[(size_t)row * D + col0 + tx]) = o;
            }
        }
    }
}

// ---------------- fused edge-score + online-softmax + aggregation ----------------
// One wave per destination node; 4 nodes per 256-thread block.
// Lane l owns dims {2l, 2l+1}; head = l>>3; e-reduce = 3 shfl_xor within 8 lanes.
// xl gathered as fp16-packed uint (2 dims / 4B per lane = 256B per row per wave).

#define FUSED_UPDATE(vv)                                                        \
    {                                                                           \
        float2 vf = __half22float2(*reinterpret_cast<const __half2*>(&(vv)));   \
        float v0 = vf.x, v1 = vf.y;                                             \
        float t0 = v0 + r0;                                                     \
        float t1 = v1 + r1;                                                     \
        float e = (fmaxf(t0, 0.f) + SLOPE * fminf(t0, 0.f)) * a0               \
                + (fmaxf(t1, 0.f) + SLOPE * fminf(t1, 0.f)) * a1;              \
        e += __shfl_xor(e, 1);                                                  \
        e += __shfl_xor(e, 2);                                                  \
        e += __shfl_xor(e, 4);                                                  \
        float dd = e - m0;                                                      \
        float ex = __expf(-fabsf(dd));                                          \
        float p = (dd <= 0.f) ? ex : 1.f;                                       \
        float c = (dd <= 0.f) ? 1.f : ex;                                       \
        m0 = fmaxf(m0, e);                                                      \
        s0 = s0 * c + p;                                                        \
        acc0 = acc0 * c + p * v0;                                               \
        acc1 = acc1 * c + p * v1;                                               \
    }

__global__ __launch_bounds__(256) void k_fused(const int* __restrict__ offsets,
                                               const int* __restrict__ srcs,
                                               const uint32* __restrict__ xlh,
                                               const float* __restrict__ xr,
                                               const float* __restrict__ att,
                                               const float* __restrict__ bias,
                                               float* __restrict__ xout) {
    const int lane = threadIdx.x & 63;
    const int n = blockIdx.x * 4 + (threadIdx.x >> 6);
    const int off = offsets[n];
    const int deg = offsets[n + 1] - off;

    float2 rr = *reinterpret_cast<const float2*>(&xr[(size_t)n * D + 2 * lane]);
    const float r0 = rr.x, r1 = rr.y;
    float2 aa = *reinterpret_cast<const float2*>(&att[2 * lane]);
    const float a0 = aa.x, a1 = aa.y;

    float m0 = -1e30f;
    float s0 = 0.f;
    float acc0 = 0.f, acc1 = 0.f;

    int i = 0;
    int peel = (4 - (off & 3)) & 3;
    if (peel > deg) peel = deg;
    for (; i < peel; ++i) {
        uint32 vv = xlh[(size_t)srcs[off + i] * 64 + lane];
        FUSED_UPDATE(vv);
    }
    for (; i + 8 <= deg; i += 8) {
        int4 sq0 = *reinterpret_cast<const int4*>(&srcs[off + i]);
        int4 sq1 = *reinterpret_cast<const int4*>(&srcs[off + i + 4]);
        int sa[8] = {sq0.x, sq0.y, sq0.z, sq0.w, sq1.x, sq1.y, sq1.z, sq1.w};
        uint32 vv[8];
#pragma unroll
        for (int j = 0; j < 8; ++j) vv[j] = xlh[(size_t)sa[j] * 64 + lane];
#pragma unroll
        for (int j = 0; j < 8; ++j) FUSED_UPDATE(vv[j]);
    }
    for (; i + 4 <= deg; i += 4) {
        int4 sq = *reinterpret_cast<const int4*>(&srcs[off + i]);
        int sa[4] = {sq.x, sq.y, sq.z, sq.w};
        uint32 vv[4];
#pragma unroll
        for (int j = 0; j < 4; ++j) vv[j] = xlh[(size_t)sa[j] * 64 + lane];
#pragma unroll
        for (int j = 0; j < 4; ++j) FUSED_UPDATE(vv[j]);
    }
    for (; i < deg; ++i) {
        uint32 vv = xlh[(size_t)srcs[off + i] * 64 + lane];
        FUSED_UPDATE(vv);
    }

    float inv = 1.f / (s0 + 1e-16f);
    float2 bb = *reinterpret_cast<const float2*>(&bias[2 * lane]);
    float2 oo;
    oo.x = acc0 * inv + bb.x;
    oo.y = acc1 * inv + bb.y;
    *reinterpret_cast<float2*>(&xout[(size_t)n * D + 2 * lane]) = oo;
}

// ---------------- output head ----------------

__global__ void k_out(const float* __restrict__ x, const float* __restrict__ Wout,
                      const float* __restrict__ bout, float* __restrict__ y) {
    int lane = threadIdx.x;
#pragma unroll
    for (int i = 0; i < 2; ++i) {
        float v = x[i * D + lane] * Wout[lane] + x[i * D + 64 + lane] * Wout[64 + lane];
        v += __shfl_xor(v, 1); v += __shfl_xor(v, 2); v += __shfl_xor(v, 4);
        v += __shfl_xor(v, 8); v += __shfl_xor(v, 16); v += __shfl_xor(v, 32);
        if (lane == 0) y[i] = v + bout[0];
    }
}

// ---------------- launch ----------------

extern "C" void kernel_launch(void* const* d_in, const int* in_sizes, int n_in,
                              void* d_out, int out_size, void* d_ws, size_t ws_size,
                              hipStream_t stream) {
    const float* x_in = (const float*)d_in[0];
    const int*   ei   = (const int*)d_in[1];
    const float* Wl   = (const float*)d_in[2];
    const float* bl   = (const float*)d_in[3];
    const float* Wr   = (const float*)d_in[4];
    const float* br   = (const float*)d_in[5];
    const float* att  = (const float*)d_in[6];
    const float* bias = (const float*)d_in[7];
    const float* Wout = (const float*)d_in[8];
    const float* bout = (const float*)d_in[9];
    float* y = (float*)d_out;

    char* ws = (char*)d_ws;
    size_t o = 0;
    auto alloc = [&](size_t bytes) -> void* {
        void* p = ws + o;
        o = (o + bytes + 255) & ~(size_t)255;
        return p;
    };
    float* xb0 = (float*)alloc((size_t)NN * D * 4);
    float* xb1 = (float*)alloc((size_t)NN * D * 4);
    ushort* xlh = (ushort*)alloc((size_t)NN * D * 2);
    float* xr   = (float*)alloc((size_t)NN * D * 4);
    int* counts   = (int*)alloc((size_t)NN * 4);
    int* offsets  = (int*)alloc(((size_t)NN + 1) * 4);
    int* cursor   = (int*)alloc((size_t)NN * 4);
    int* srcs     = (int*)alloc((size_t)ET * 4);
    int* partials = (int*)alloc(256 * 4);
    (void)ws_size; (void)in_sizes; (void)n_in; (void)out_size;

    // CSR by dst with resolved srcs (layer-invariant)
    k_zero<<<NB_SCAN, 256, 0, stream>>>(counts, NN);
    k_hist<<<(ET + 255) / 256, 256, 0, stream>>>(ei, counts);
    k_scan1<<<NB_SCAN, 256, 0, stream>>>(counts, offsets, partials);
    k_scan2<<<1, 128, 0, stream>>>(partials, offsets);
    k_scan3<<<NB_SCAN, 256, 0, stream>>>(partials, offsets, cursor);
    k_scatter<<<(ET + 255) / 256, 256, 0, stream>>>(ei, cursor, srcs);

    const int ggrid = (NN + 63) / 64;
    for (int i = 0; i < NL; ++i) {
        const float* xin = (i == 0) ? x_in : ((i & 1) ? xb0 : xb1);
        float* xout = (i & 1) ? xb1 : xb0;
        k_gemm<<<ggrid, 256, 0, stream>>>(xin, Wl + (size_t)i * D * D, bl + i * D,
                                          Wr + (size_t)i * D * D, br + i * D, xlh, xr);
        k_fused<<<NN / 4, 256, 0, stream>>>(offsets, srcs, (const uint32*)xlh, xr,
                                            att + i * NH * HD, bias + i * D, xout);
    }
    k_out<<<1, 64, 0, stream>>>(xb0, Wout, bout, y);  // NL=7 odd -> final in xb0
}

// Round 6
// 496.269 us; speedup vs baseline: 2.7806x; 1.1265x over previous
//
#include <hip/hip_runtime.h>
#include <hip/hip_fp16.h>

#define NN 30000
#define ER 480000
#define ET 510000           // ER + NN self-loops
#define D 128
#define NH 8
#define HD 16
#define NL 7
#define SLOPE 0.2f
#define NB_SCAN 118         // ceil(NN/256)

typedef unsigned int uint32;
typedef unsigned short ushort;
typedef __attribute__((ext_vector_type(8))) short short8;
typedef __attribute__((ext_vector_type(4))) float f32x4;

__device__ inline ushort f2bf(float f) {
    uint32 u = __float_as_uint(f);
    return (ushort)((u + 0x7fffu + ((u >> 16) & 1u)) >> 16);   // RNE
}

// ---------------- CSR build (dst is layer-invariant) ----------------

__global__ void k_zero(int* __restrict__ p, int n) {
    int i = blockIdx.x * 256 + threadIdx.x;
    if (i < n) p[i] = 0;
}

__global__ void k_hist(const int* __restrict__ ei, int* __restrict__ counts) {
    int i = blockIdx.x * 256 + threadIdx.x;
    if (i >= ET) return;
    int dst = (i < ER) ? ei[ER + i] : (i - ER);
    atomicAdd(&counts[dst], 1);
}

__global__ __launch_bounds__(256) void k_scan1(const int* __restrict__ counts,
                                               int* __restrict__ offsets,
                                               int* __restrict__ partials) {
    int t = threadIdx.x;
    int i = blockIdx.x * 256 + t;
    int v = (i < NN) ? counts[i] : 0;
    int lane = t & 63;
    int incl = v;
#pragma unroll
    for (int d = 1; d < 64; d <<= 1) {
        int u = __shfl_up(incl, d);
        if (lane >= d) incl += u;
    }
    __shared__ int ws[4];
    if (lane == 63) ws[t >> 6] = incl;
    __syncthreads();
    int wid = t >> 6;
    int base = 0;
    if (wid > 0) base += ws[0];
    if (wid > 1) base += ws[1];
    if (wid > 2) base += ws[2];
    if (i < NN) offsets[i] = base + incl - v;
    if (t == 255) partials[blockIdx.x] = base + incl;
}

__global__ __launch_bounds__(128) void k_scan2(int* __restrict__ partials,
                                               int* __restrict__ offsets) {
    int t = threadIdx.x;
    int v = (t < NB_SCAN) ? partials[t] : 0;
    int lane = t & 63;
    int incl = v;
#pragma unroll
    for (int d = 1; d < 64; d <<= 1) {
        int u = __shfl_up(incl, d);
        if (lane >= d) incl += u;
    }
    __shared__ int w0;
    if (t == 63) w0 = incl;
    __syncthreads();
    int base = (t >= 64) ? w0 : 0;
    if (t < NB_SCAN) partials[t] = base + incl - v;
    if (t == 127) offsets[NN] = base + incl;
}

__global__ void k_scan3(const int* __restrict__ partials, int* __restrict__ offsets,
                        int* __restrict__ cursor) {
    int i = blockIdx.x * 256 + threadIdx.x;
    if (i < NN) {
        int o = offsets[i] + partials[blockIdx.x];
        offsets[i] = o;
        cursor[i] = o;
    }
}

__global__ void k_scatter(const int* __restrict__ ei, int* __restrict__ cursor,
                          int* __restrict__ srcs) {
    int i = blockIdx.x * 256 + threadIdx.x;
    if (i >= ET) return;
    int src, dst;
    if (i < ER) { src = ei[i]; dst = ei[ER + i]; }
    else        { src = i - ER; dst = src; }
    int pos = atomicAdd(&cursor[dst], 1);
    srcs[pos] = src;
}

// ---------------- W prep: transpose + bf16 hi/lo split, once for all layers ----------
// Wt[n][k], n in [0,256): n<128 -> Wl col n; n>=128 -> Wr col n-128.

__global__ __launch_bounds__(256) void k_wprep(const float* __restrict__ Wl,
                                               const float* __restrict__ Wr,
                                               ushort* __restrict__ Wth,
                                               ushort* __restrict__ Wtl) {
    int bx = blockIdx.x;              // NL*8 blocks
    int layer = bx >> 3;
    int n0 = (bx & 7) * 32;
    const float* WL = Wl + (size_t)layer * D * D;
    const float* WR = Wr + (size_t)layer * D * D;
    ushort* th = Wth + (size_t)layer * 256 * 128;
    ushort* tl = Wtl + (size_t)layer * 256 * 128;
    for (int idx = threadIdx.x; idx < 32 * 128; idx += 256) {
        int n = n0 + (idx >> 7);
        int k = idx & 127;
        float w = (n < 128) ? WL[k * 128 + n] : WR[k * 128 + (n - 128)];
        ushort h = f2bf(w);
        float hf = __uint_as_float(((uint32)h) << 16);
        ushort e = f2bf(w - hf);
        th[n * 128 + k] = h;
        tl[n * 128 + k] = e;
    }
}

// ---------------- MFMA split-bf16 GEMM: [xl | xr] = X @ [Wl | Wr] + [bl | br] -------
// grid (469, 4): 64-row tile x 64-col chunk of the 256-wide concat output.
// wave w handles rows [w*16, w*16+16); 4 nc sub-tiles of 16 cols; K=128 in 4 chunks.
// X@W ~= Xh@Wh + Xh@We + Xe@Wh  (bf16 hi/lo split, fp32 accumulate, ~2^-17 rel err).

__global__ __launch_bounds__(256) void k_mm(const float* __restrict__ X,
                                            const ushort* __restrict__ Wth,
                                            const ushort* __restrict__ Wtl,
                                            const float* __restrict__ bl,
                                            const float* __restrict__ br,
                                            ushort* __restrict__ xlh,
                                            float* __restrict__ xr) {
    __shared__ float  Xs[64][132];     // pad 132: 2-way bank alias only
    __shared__ ushort Wh[64][136];     // pad 136: 16B-aligned rows, 2-way alias
    __shared__ ushort We[64][136];
    const int row0 = blockIdx.x * 64;
    const int nq = blockIdx.y;         // col chunk [nq*64, nq*64+64) of 256
    const int tid = threadIdx.x;
    // stage X tile (row-major fp32)
    {
        int r = tid >> 2;
        int c4 = (tid & 3) * 4;
        int row = row0 + r; if (row >= NN) row = NN - 1;
        const float* xp = X + (size_t)row * D;
#pragma unroll
        for (int pass = 0; pass < 8; ++pass) {
            int c = pass * 16 + c4;
            *reinterpret_cast<float4*>(&Xs[r][c]) = *reinterpret_cast<const float4*>(xp + c);
        }
    }
    // stage W chunk rows [nq*64, nq*64+64), hi and lo
    {
        int nn = tid >> 2;
        int ch = tid & 3;
        const ushort* wh = Wth + (size_t)(nq * 64 + nn) * 128;
        const ushort* wl = Wtl + (size_t)(nq * 64 + nn) * 128;
#pragma unroll
        for (int pass = 0; pass < 4; ++pass) {
            int ko = (ch * 4 + pass) * 8;
            *reinterpret_cast<uint4*>(&Wh[nn][ko]) = *reinterpret_cast<const uint4*>(wh + ko);
            *reinterpret_cast<uint4*>(&We[nn][ko]) = *reinterpret_cast<const uint4*>(wl + ko);
        }
    }
    __syncthreads();

    const int wv = tid >> 6;
    const int l  = tid & 63;
    const int lr = l & 15;             // A row / B col / C col
    const int kg = (l >> 4) * 8;       // k-group base within 32-chunk
    f32x4 acc[4] = {};
#pragma unroll
    for (int kc = 0; kc < 4; ++kc) {
        short8 Ah, Ae;
        const float* xrow = &Xs[wv * 16 + lr][kc * 32 + kg];
#pragma unroll
        for (int j = 0; j < 8; ++j) {
            float x = xrow[j];
            ushort h = f2bf(x);
            float hf = __uint_as_float(((uint32)h) << 16);
            Ah[j] = (short)h;
            Ae[j] = (short)f2bf(x - hf);
        }
#pragma unroll
        for (int nc = 0; nc < 4; ++nc) {
            short8 Bh = *reinterpret_cast<const short8*>(&Wh[nc * 16 + lr][kc * 32 + kg]);
            short8 Be = *reinterpret_cast<const short8*>(&We[nc * 16 + lr][kc * 32 + kg]);
            acc[nc] = __builtin_amdgcn_mfma_f32_16x16x32_bf16(Ah, Bh, acc[nc], 0, 0, 0);
            acc[nc] = __builtin_amdgcn_mfma_f32_16x16x32_bf16(Ah, Be, acc[nc], 0, 0, 0);
            acc[nc] = __builtin_amdgcn_mfma_f32_16x16x32_bf16(Ae, Bh, acc[nc], 0, 0, 0);
        }
    }
    // epilogue: C/D layout col=lane&15, row=(lane>>4)*4+reg
    const int rbase = row0 + wv * 16 + (l >> 4) * 4;
#pragma unroll
    for (int nc = 0; nc < 4; ++nc) {
        int g = nq * 64 + nc * 16 + lr;   // col in 256-concat (uniform branch: nq<2 <=> g<128)
        if (g < 128) {
            float bb = bl[g];
#pragma unroll
            for (int j = 0; j < 4; ++j) {
                int row = rbase + j;
                if (row < NN)
                    xlh[(size_t)row * D + g] = __half_as_ushort(__float2half_rn(acc[nc][j] + bb));
            }
        } else {
            float bb = br[g - 128];
#pragma unroll
            for (int j = 0; j < 4; ++j) {
                int row = rbase + j;
                if (row < NN)
                    xr[(size_t)row * D + (g - 128)] = acc[nc][j] + bb;
            }
        }
    }
}

// ---------------- fused edge-score + online-softmax + aggregation ----------------
// One wave per destination node; 4 nodes per 256-thread block.
// Lane l owns dims {2l, 2l+1}; head = l>>3; e-reduce = 3 shfl_xor within 8 lanes.

#define FUSED_UPDATE(vv)                                                        \
    {                                                                           \
        float2 vf = __half22float2(*reinterpret_cast<const __half2*>(&(vv)));   \
        float v0 = vf.x, v1 = vf.y;                                             \
        float t0 = v0 + r0;                                                     \
        float t1 = v1 + r1;                                                     \
        float e = (fmaxf(t0, 0.f) + SLOPE * fminf(t0, 0.f)) * a0               \
                + (fmaxf(t1, 0.f) + SLOPE * fminf(t1, 0.f)) * a1;              \
        e += __shfl_xor(e, 1);                                                  \
        e += __shfl_xor(e, 2);                                                  \
        e += __shfl_xor(e, 4);                                                  \
        float dd = e - m0;                                                      \
        float ex = __expf(-fabsf(dd));                                          \
        float p = (dd <= 0.f) ? ex : 1.f;                                       \
        float c = (dd <= 0.f) ? 1.f : ex;                                       \
        m0 = fmaxf(m0, e);                                                      \
        s0 = s0 * c + p;                                                        \
        acc0 = acc0 * c + p * v0;                                               \
        acc1 = acc1 * c + p * v1;                                               \
    }

__global__ __launch_bounds__(256) void k_fused(const int* __restrict__ offsets,
                                               const int* __restrict__ srcs,
                                               const uint32* __restrict__ xlh,
                                               const float* __restrict__ xr,
                                               const float* __restrict__ att,
                                               const float* __restrict__ bias,
                                               float* __restrict__ xout) {
    const int lane = threadIdx.x & 63;
    const int n = blockIdx.x * 4 + (threadIdx.x >> 6);
    const int off = offsets[n];
    const int deg = offsets[n + 1] - off;

    float2 rr = *reinterpret_cast<const float2*>(&xr[(size_t)n * D + 2 * lane]);
    const float r0 = rr.x, r1 = rr.y;
    float2 aa = *reinterpret_cast<const float2*>(&att[2 * lane]);
    const float a0 = aa.x, a1 = aa.y;

    float m0 = -1e30f;
    float s0 = 0.f;
    float acc0 = 0.f, acc1 = 0.f;

    int i = 0;
    int peel = (4 - (off & 3)) & 3;
    if (peel > deg) peel = deg;
    for (; i < peel; ++i) {
        uint32 vv = xlh[(size_t)srcs[off + i] * 64 + lane];
        FUSED_UPDATE(vv);
    }
    for (; i + 8 <= deg; i += 8) {
        int4 sq0 = *reinterpret_cast<const int4*>(&srcs[off + i]);
        int4 sq1 = *reinterpret_cast<const int4*>(&srcs[off + i + 4]);
        int sa[8] = {sq0.x, sq0.y, sq0.z, sq0.w, sq1.x, sq1.y, sq1.z, sq1.w};
        uint32 vv[8];
#pragma unroll
        for (int j = 0; j < 8; ++j) vv[j] = xlh[(size_t)sa[j] * 64 + lane];
#pragma unroll
        for (int j = 0; j < 8; ++j) FUSED_UPDATE(vv[j]);
    }
    for (; i + 4 <= deg; i += 4) {
        int4 sq = *reinterpret_cast<const int4*>(&srcs[off + i]);
        int sa[4] = {sq.x, sq.y, sq.z, sq.w};
        uint32 vv[4];
#pragma unroll
        for (int j = 0; j < 4; ++j) vv[j] = xlh[(size_t)sa[j] * 64 + lane];
#pragma unroll
        for (int j = 0; j < 4; ++j) FUSED_UPDATE(vv[j]);
    }
    for (; i < deg; ++i) {
        uint32 vv = xlh[(size_t)srcs[off + i] * 64 + lane];
        FUSED_UPDATE(vv);
    }

    float inv = 1.f / (s0 + 1e-16f);
    float2 bb = *reinterpret_cast<const float2*>(&bias[2 * lane]);
    float2 oo;
    oo.x = acc0 * inv + bb.x;
    oo.y = acc1 * inv + bb.y;
    *reinterpret_cast<float2*>(&xout[(size_t)n * D + 2 * lane]) = oo;
}

// ---------------- output head ----------------

__global__ void k_out(const float* __restrict__ x, const float* __restrict__ Wout,
                      const float* __restrict__ bout, float* __restrict__ y) {
    int lane = threadIdx.x;
#pragma unroll
    for (int i = 0; i < 2; ++i) {
        float v = x[i * D + lane] * Wout[lane] + x[i * D + 64 + lane] * Wout[64 + lane];
        v += __shfl_xor(v, 1); v += __shfl_xor(v, 2); v += __shfl_xor(v, 4);
        v += __shfl_xor(v, 8); v += __shfl_xor(v, 16); v += __shfl_xor(v, 32);
        if (lane == 0) y[i] = v + bout[0];
    }
}

// ---------------- launch ----------------

extern "C" void kernel_launch(void* const* d_in, const int* in_sizes, int n_in,
                              void* d_out, int out_size, void* d_ws, size_t ws_size,
                              hipStream_t stream) {
    const float* x_in = (const float*)d_in[0];
    const int*   ei   = (const int*)d_in[1];
    const float* Wl   = (const float*)d_in[2];
    const float* bl   = (const float*)d_in[3];
    const float* Wr   = (const float*)d_in[4];
    const float* br   = (const float*)d_in[5];
    const float* att  = (const float*)d_in[6];
    const float* bias = (const float*)d_in[7];
    const float* Wout = (const float*)d_in[8];
    const float* bout = (const float*)d_in[9];
    float* y = (float*)d_out;

    char* ws = (char*)d_ws;
    size_t o = 0;
    auto alloc = [&](size_t bytes) -> void* {
        void* p = ws + o;
        o = (o + bytes + 255) & ~(size_t)255;
        return p;
    };
    float* xb0 = (float*)alloc((size_t)NN * D * 4);
    float* xb1 = (float*)alloc((size_t)NN * D * 4);
    ushort* xlh = (ushort*)alloc((size_t)NN * D * 2);
    float* xr   = (float*)alloc((size_t)NN * D * 4);
    ushort* Wth = (ushort*)alloc((size_t)NL * 256 * 128 * 2);
    ushort* Wtl = (ushort*)alloc((size_t)NL * 256 * 128 * 2);
    int* counts   = (int*)alloc((size_t)NN * 4);
    int* offsets  = (int*)alloc(((size_t)NN + 1) * 4);
    int* cursor   = (int*)alloc((size_t)NN * 4);
    int* srcs     = (int*)alloc((size_t)ET * 4);
    int* partials = (int*)alloc(256 * 4);
    (void)ws_size; (void)in_sizes; (void)n_in; (void)out_size;

    // CSR by dst with resolved srcs (layer-invariant) + W prep
    k_zero<<<NB_SCAN, 256, 0, stream>>>(counts, NN);
    k_hist<<<(ET + 255) / 256, 256, 0, stream>>>(ei, counts);
    k_scan1<<<NB_SCAN, 256, 0, stream>>>(counts, offsets, partials);
    k_scan2<<<1, 128, 0, stream>>>(partials, offsets);
    k_scan3<<<NB_SCAN, 256, 0, stream>>>(partials, offsets, cursor);
    k_scatter<<<(ET + 255) / 256, 256, 0, stream>>>(ei, cursor, srcs);
    k_wprep<<<NL * 8, 256, 0, stream>>>(Wl, Wr, Wth, Wtl);

    const int mgrid = (NN + 63) / 64;   // 469
    for (int i = 0; i < NL; ++i) {
        const float* xin = (i == 0) ? x_in : ((i & 1) ? xb0 : xb1);
        float* xout = (i & 1) ? xb1 : xb0;
        k_mm<<<dim3(mgrid, 4), 256, 0, stream>>>(xin,
                                                 Wth + (size_t)i * 256 * 128,
                                                 Wtl + (size_t)i * 256 * 128,
                                                 bl + i * D, br + i * D, xlh, xr);
        k_fused<<<NN / 4, 256, 0, stream>>>(offsets, srcs, (const uint32*)xlh, xr,
                                            att + i * NH * HD, bias + i * D, xout);
    }
    k_out<<<1, 64, 0, stream>>>(xb0, Wout, bout, y);  // NL=7 odd -> final in xb0
}